// Round 1
// baseline (212.593 us; speedup 1.0000x reference)
//
#include <hip/hip_runtime.h>

// Problem geometry (fixed by setup_inputs): batch=256, N=65536, x is (256, 2N), w is (16, N).
#define NCOLS 65536
#define BATCH 256

// Kernel 1: per-column softmax over 16 gate logits, folded through the constant
// W16_TO_4 matrix. One thread per column; loads of w[j*N + n] are coalesced
// across threads for each j. Output stored planar: wc[k*N + n], k=0..3.
__global__ void gate_precompute(const float* __restrict__ w, float* __restrict__ wc) {
    int n = blockIdx.x * blockDim.x + threadIdx.x;
    if (n >= NCOLS) return;
    float e[16];
    float m = -INFINITY;
#pragma unroll
    for (int j = 0; j < 16; ++j) {
        e[j] = w[j * NCOLS + n];
        m = fmaxf(m, e[j]);
    }
    float s = 0.f;
#pragma unroll
    for (int j = 0; j < 16; ++j) {
        e[j] = __expf(e[j] - m);
        s += e[j];
    }
    float inv = 1.0f / s;
    // Rows of W16_TO_4 hardcoded (see reference _w16_to_4):
    float c0 = (e[8] + e[9] + e[10] + e[11] + e[12] + e[13] + e[14] + e[15]) * inv;
    float c1 = (e[2] + e[3] + e[6] + e[7] - e[8] - e[9] - e[12] - e[13]) * inv;
    float c2 = (e[4] + e[5] + e[6] + e[7] - e[8] - e[9] - e[10] - e[11]) * inv;
    float c3 = (e[1] - e[2] - e[4] - 2.f * e[6] - e[7] + e[8] + 2.f * e[9] + e[11] + e[13] - e[14]) * inv;
    wc[0 * NCOLS + n] = c0;
    wc[1 * NCOLS + n] = c1;
    wc[2 * NCOLS + n] = c2;
    wc[3 * NCOLS + n] = c3;
}

// Kernel 2: memory-bound apply. Each thread produces 4 consecutive outputs of
// one row: reads 2x float4 from x (A/B interleaved), 4x float4 of coefficients
// (L2-resident, reused across the 256 batch rows), writes 1x float4.
__global__ void gate_apply(const float* __restrict__ x,
                           const float* __restrict__ wc,
                           float* __restrict__ out) {
    int tid = blockIdx.x * blockDim.x + threadIdx.x;   // one thread per 4 outputs
    // i4 = tid*4 = b*N + n ; N = 2^16, so:
    int b = tid >> 14;            // (tid*4) >> 16
    int n = (tid & 16383) << 2;   // (tid*4) & 65535, multiple of 4
    const float4* xp = (const float4*)(x + (size_t)b * (2 * NCOLS) + 2 * (size_t)n);
    float4 x0 = xp[0];  // A[n], B[n], A[n+1], B[n+1]
    float4 x1 = xp[1];  // A[n+2], B[n+2], A[n+3], B[n+3]
    float4 c0 = *(const float4*)(wc + 0 * NCOLS + n);
    float4 c1 = *(const float4*)(wc + 1 * NCOLS + n);
    float4 c2 = *(const float4*)(wc + 2 * NCOLS + n);
    float4 c3 = *(const float4*)(wc + 3 * NCOLS + n);
    float4 o;
    o.x = c0.x + c1.x * x0.x + c2.x * x0.y + c3.x * (x0.x * x0.y);
    o.y = c0.y + c1.y * x0.z + c2.y * x0.w + c3.y * (x0.z * x0.w);
    o.z = c0.z + c1.z * x1.x + c2.z * x1.y + c3.z * (x1.x * x1.y);
    o.w = c0.w + c1.w * x1.z + c2.w * x1.w + c3.w * (x1.z * x1.w);
    *(float4*)(out + (size_t)tid * 4) = o;
}

extern "C" void kernel_launch(void* const* d_in, const int* in_sizes, int n_in,
                              void* d_out, int out_size, void* d_ws, size_t ws_size,
                              hipStream_t stream) {
    const float* x = (const float*)d_in[0];   // (256, 131072) fp32
    const float* w = (const float*)d_in[1];   // (16, 65536) fp32
    float* out = (float*)d_out;               // (256, 65536) fp32
    float* wc = (float*)d_ws;                 // 4 * 65536 fp32 = 1 MiB scratch

    gate_precompute<<<NCOLS / 256, 256, 0, stream>>>(w, wc);

    const int total4 = (BATCH * NCOLS) / 4;   // 4,194,304 threads
    gate_apply<<<total4 / 256, 256, 0, stream>>>(x, wc, out);
}